// Round 7
// baseline (1576.005 us; speedup 1.0000x reference)
//
#include <hip/hip_runtime.h>
#include <cstdint>

#define TT 24

typedef short short8 __attribute__((ext_vector_type(8)));
typedef float f32x4 __attribute__((ext_vector_type(4)));

static __device__ __forceinline__ float fsig(float x){
  float e = __builtin_amdgcn_exp2f(-1.44269504f*x);
  return __builtin_amdgcn_rcpf(1.0f + e);
}
static __device__ __forceinline__ float ftanh(float x){
  float e = __builtin_amdgcn_exp2f(-2.88539008f*x);
  return fmaf(2.0f, __builtin_amdgcn_rcpf(1.0f + e), -1.0f);
}
static __device__ __forceinline__ float lrelu(float x){ return x > 0.f ? x : 0.2f*x; }

static __device__ __forceinline__ int swzh(int b){ return b ^ (((b>>7)&7)<<4); }
static __device__ __forceinline__ unsigned short f2bf(float f){
  unsigned u = __float_as_uint(f);
  u += 0x7FFF + ((u>>16)&1);
  return (unsigned short)(u>>16);
}
static __device__ __forceinline__ float bf2f(unsigned short h){
  return __uint_as_float(((unsigned)h)<<16);
}

// ---------------- prep: B-fragment build (split bf16) + linwT + cE ----------------
// Bhi/Blo[((mat*2+c)*16+nt16)*512 + l*8 + j] = split of W[k=32c+8*(l>>4)+j][col=16*nt16+(l&15)]
// where W[k][col] = wsrc[col*64+k]; mat 0=w_hh0, 1=w_ih1, 2=w_hh1. col = gate*64+jp.
__global__ void kPrep(const float* __restrict__ w_hh0, const float* __restrict__ w_ih1,
                      const float* __restrict__ w_hh1, const float* __restrict__ lin_w,
                      const float* __restrict__ lin_edge_w, const float* __restrict__ att_edge,
                      unsigned short* __restrict__ Bhi, unsigned short* __restrict__ Blo,
                      float* __restrict__ linwT, float* __restrict__ cE)
{
  int gid = blockIdx.x*256 + threadIdx.x;
  if (gid < 49152){
    int mat = gid / 16384;
    int r = gid - mat*16384;
    int c = r>>13, nt = (r>>9)&15, l = (r>>3)&63, j = r&7;
    int k = c*32 + (l>>4)*8 + j;
    int col = nt*16 + (l&15);
    const float* wsrc = (mat==0) ? w_hh0 : (mat==1 ? w_ih1 : w_hh1);
    float v = wsrc[col*64 + k];
    unsigned short hb = f2bf(v);
    unsigned short lb = f2bf(v - bf2f(hb));
    Bhi[gid] = hb;
    Blo[gid] = lb;
  }
  int g2 = gid - 49152;
  if (g2 >= 0 && g2 < 72*128){
    int k = g2 >> 7, ch = g2 & 127;
    linwT[g2] = lin_w[ch*72 + k];
  }
  if (gid >= 58368 && gid < 58372){
    int h = gid - 58368;
    float s = 0.f;
    for (int c=0;c<32;c++) s += lin_edge_w[h*32+c]*att_edge[h*32+c];
    cE[h] = s;
  }
}

// ---------------- fused 2-layer LSTM via MFMA, gate-major, in-register nonlin ----------------
// 64 nodes/block, 256 threads = 4 waves. Wave wv owns jp = wv*16+lr across ALL 4 gates
// (col = nt*64 + wv*16 + lr, nt = gate). Nonlinearity fully in registers (no sPre).
// h state in LDS as bf16 hi/lo, XOR-swizzled. 3 barriers/step.
// A/B k-slot convention (verified R6): k = c*32 + (lane>>4)*8 + j for both operands.
// C/D: col=lane&15, row=(lane>>4)*4+reg (m89).
__global__ __launch_bounds__(256,2) void kAB(const float* __restrict__ x,
    const unsigned short* __restrict__ Bhi, const unsigned short* __restrict__ Blo,
    const float* __restrict__ w_ih0, const float* __restrict__ b_ih0, const float* __restrict__ b_hh0,
    const float* __restrict__ b_ih1, const float* __restrict__ b_hh1,
    float* __restrict__ h2last, int N)
{
  __shared__ __align__(16) unsigned short sH1h[4096];   // [64 node][64 jp] bf16-hi
  __shared__ __align__(16) unsigned short sH1l[4096];
  __shared__ __align__(16) unsigned short sH2h[4096];
  __shared__ __align__(16) unsigned short sH2l[4096];
  __shared__ float sX[64*25];                           // padded stride 25
  const int tid = threadIdx.x;
  const int wv = tid>>6, l = tid&63;
  const int lr = l&15, lg = l>>4;
  const int nb = blockIdx.x*64;

  for (int i=tid;i<64*24;i+=256){
    int m = i/24, tt = i - m*24;
    int n = nb + m;
    sX[m*25+tt] = (n<N) ? x[(size_t)n*32 + 8 + tt] : 0.f;
  }
  for (int i=tid;i<4096;i+=256){ sH1h[i]=0; sH1l[i]=0; sH2h[i]=0; sH2l[i]=0; }

  float wih[4], bb0[4], bb1[4];
  #pragma unroll
  for (int nt=0;nt<4;nt++){
    int col = nt*64 + wv*16 + lr;
    wih[nt] = w_ih0[col];
    bb0[nt] = b_ih0[col] + b_hh0[col];
    bb1[nt] = b_ih1[col] + b_hh1[col];
  }
  float cc0[16], cc1[16];
  #pragma unroll
  for (int i=0;i<16;i++){ cc0[i]=0.f; cc1[i]=0.f; }
  __syncthreads();

  const char* h1hB = (const char*)sH1h;
  const char* h1lB = (const char*)sH1l;
  const char* h2hB = (const char*)sH2h;
  const char* h2lB = (const char*)sH2l;

  for (int t=0;t<TT;t++){
    // ================= GEMM0: preact0 = h1(t-1)*W0 + x_t*wih + b  (in-reg) =================
    f32x4 acc[4][4];
    #pragma unroll
    for (int mt=0;mt<4;mt++){
      #pragma unroll
      for (int r=0;r<4;r++){
        float xv = sX[(mt*16 + lg*4 + r)*25 + t];
        #pragma unroll
        for (int nt=0;nt<4;nt++) acc[mt][nt][r] = fmaf(xv, wih[nt], bb0[nt]);
      }
    }
    #pragma unroll
    for (int c=0;c<2;c++){
      short8 aH[4], aL[4];
      #pragma unroll
      for (int mt=0;mt<4;mt++){
        int by = swzh((mt*16+lr)*128 + c*64 + lg*16);
        aH[mt] = *(const short8*)(h1hB + by);
        aL[mt] = *(const short8*)(h1lB + by);
      }
      #pragma unroll
      for (int nt=0;nt<4;nt++){
        int off = ((c*16 + nt*4 + wv)<<9) + l*8;
        short8 bH = *(const short8*)&Bhi[off];
        short8 bL = *(const short8*)&Blo[off];
        #pragma unroll
        for (int mt=0;mt<4;mt++){
          acc[mt][nt] = __builtin_amdgcn_mfma_f32_16x16x32_bf16(aH[mt], bH, acc[mt][nt], 0,0,0);
          acc[mt][nt] = __builtin_amdgcn_mfma_f32_16x16x32_bf16(aH[mt], bL, acc[mt][nt], 0,0,0);
          acc[mt][nt] = __builtin_amdgcn_mfma_f32_16x16x32_bf16(aL[mt], bH, acc[mt][nt], 0,0,0);
        }
      }
    }
    __syncthreads();   // B1: all waves done reading sH1(t-1)
    // ================= nonlin0 (in registers) -> write h1(t) =================
    #pragma unroll
    for (int mt=0;mt<4;mt++){
      #pragma unroll
      for (int r=0;r<4;r++){
        int idx = mt*4+r, nd = mt*16 + lg*4 + r;
        float ig = fsig(acc[mt][0][r]), fg = fsig(acc[mt][1][r]);
        float gg = ftanh(acc[mt][2][r]), og = fsig(acc[mt][3][r]);
        cc0[idx] = fg*cc0[idx] + ig*gg;
        float h = og*ftanh(cc0[idx]);
        unsigned u = __float_as_uint(h);
        unsigned short hb = (unsigned short)(u>>16);
        float d = h - __uint_as_float(u & 0xFFFF0000u);
        unsigned short lb = (unsigned short)(__float_as_uint(d)>>16);
        int by = swzh(nd*128 + (wv*16+lr)*2);
        *(unsigned short*)((char*)sH1h + by) = hb;
        *(unsigned short*)((char*)sH1l + by) = lb;
      }
    }
    __syncthreads();   // B2: h1(t) visible
    // ================= GEMM1: preact1 = [h1(t);h2(t-1)] * [Wih1;Whh1] + b =================
    #pragma unroll
    for (int mt=0;mt<4;mt++)
      #pragma unroll
      for (int nt=0;nt<4;nt++)
        #pragma unroll
        for (int r=0;r<4;r++) acc[mt][nt][r] = bb1[nt];
    #pragma unroll
    for (int c4=0;c4<4;c4++){
      const char* srcH = (c4<2) ? h1hB : h2hB;
      const char* srcL = (c4<2) ? h1lB : h2lB;
      int cc = c4&1;
      int matB = (c4<2) ? 32 : 64;
      short8 aH[4], aL[4];
      #pragma unroll
      for (int mt=0;mt<4;mt++){
        int by = swzh((mt*16+lr)*128 + cc*64 + lg*16);
        aH[mt] = *(const short8*)(srcH + by);
        aL[mt] = *(const short8*)(srcL + by);
      }
      #pragma unroll
      for (int nt=0;nt<4;nt++){
        int off = ((matB + cc*16 + nt*4 + wv)<<9) + l*8;
        short8 bH = *(const short8*)&Bhi[off];
        short8 bL = *(const short8*)&Blo[off];
        #pragma unroll
        for (int mt=0;mt<4;mt++){
          acc[mt][nt] = __builtin_amdgcn_mfma_f32_16x16x32_bf16(aH[mt], bH, acc[mt][nt], 0,0,0);
          acc[mt][nt] = __builtin_amdgcn_mfma_f32_16x16x32_bf16(aH[mt], bL, acc[mt][nt], 0,0,0);
          acc[mt][nt] = __builtin_amdgcn_mfma_f32_16x16x32_bf16(aL[mt], bH, acc[mt][nt], 0,0,0);
        }
      }
    }
    __syncthreads();   // B3: all waves done reading sH2(t-1)
    // ================= nonlin1 (in registers) -> write h2(t) =================
    #pragma unroll
    for (int mt=0;mt<4;mt++){
      #pragma unroll
      for (int r=0;r<4;r++){
        int idx = mt*4+r, nd = mt*16 + lg*4 + r;
        float ig = fsig(acc[mt][0][r]), fg = fsig(acc[mt][1][r]);
        float gg = ftanh(acc[mt][2][r]), og = fsig(acc[mt][3][r]);
        cc1[idx] = fg*cc1[idx] + ig*gg;
        float h = og*ftanh(cc1[idx]);
        unsigned u = __float_as_uint(h);
        unsigned short hb = (unsigned short)(u>>16);
        float d = h - __uint_as_float(u & 0xFFFF0000u);
        unsigned short lb = (unsigned short)(__float_as_uint(d)>>16);
        int by = swzh(nd*128 + (wv*16+lr)*2);
        *(unsigned short*)((char*)sH2h + by) = hb;
        *(unsigned short*)((char*)sH2l + by) = lb;
        if (t == TT-1){
          int n = nb + nd;
          if (n < N) h2last[(size_t)n*64 + wv*16 + lr] = h;
        }
      }
    }
    // no 4th barrier: next G0 reads only sH1(t) (written before B2);
    // h2(t) writes vs G1(t+1) reads are separated by B1(t+1)+B2(t+1).
  }
}

// ---------------- GAT linear + attention coefficients ----------------
__global__ __launch_bounds__(256) void kXL(const float* __restrict__ h2last, const float* __restrict__ x,
    const float* __restrict__ linwT, const float* __restrict__ att_src, const float* __restrict__ att_dst,
    float* __restrict__ xl, float* __restrict__ a_src, float* __restrict__ a_dst, int N)
{
  __shared__ float sLW[72*128];
  __shared__ float sC[16*72];
  const int tid = threadIdx.x;
  const int nb0 = blockIdx.x * 16;
  for (int i = tid*4; i < 9216; i += 1024)
    *(float4*)&sLW[i] = *(const float4*)&linwT[i];
  for (int i = tid; i < 16*64; i += 256){
    int m = i >> 6, k = i & 63; int n = nb0 + m;
    sC[m*72 + k] = (n < N) ? h2last[(size_t)n*64 + k] : 0.f;
  }
  if (tid < 128){
    int m = tid >> 3, j = tid & 7; int n = nb0 + m;
    sC[m*72 + 64 + j] = (n < N) ? x[(size_t)n*32 + j] : 0.f;
  }
  __syncthreads();
  const int ch = tid & 127, half = tid >> 7;
  float acc[8];
  #pragma unroll
  for (int m=0;m<8;m++) acc[m]=0.f;
  for (int k=0;k<72;k++){
    float w = sLW[k*128 + ch];
    #pragma unroll
    for (int m=0;m<8;m++) acc[m] += w * sC[(half*8+m)*72 + k];
  }
  float aS = att_src[ch], aD = att_dst[ch];
  int h = ch >> 5;
  #pragma unroll
  for (int m=0;m<8;m++){
    int n = nb0 + half*8 + m;
    float v = acc[m];
    float ps = v*aS, pd = v*aD;
    #pragma unroll
    for (int d=1; d<32; d<<=1){ ps += __shfl_xor(ps, d); pd += __shfl_xor(pd, d); }
    if (n < N){
      xl[(size_t)n*128 + ch] = v;
      if ((ch & 31) == 0){ a_src[n*4 + h] = ps; a_dst[n*4 + h] = pd; }
    }
  }
}

// ---------------- edge_attr mean ----------------
__global__ void kEa(const float* __restrict__ ea, float* __restrict__ acc, int E){
  int gid = blockIdx.x*blockDim.x + threadIdx.x;
  float s = 0.f;
  for (int i = gid; i < E; i += gridDim.x*blockDim.x) s += ea[i];
  #pragma unroll
  for (int d=1; d<64; d<<=1) s += __shfl_xor(s, d);
  if ((threadIdx.x & 63) == 0) atomicAdd(acc, s);
}

// ---------------- CSR build (edge_index is int32 per harness spec) ----------------
__global__ void kDeg(const int* __restrict__ dst, int* __restrict__ deg, int E, int N){
  int e = blockIdx.x*256 + threadIdx.x;
  if (e < E){
    unsigned d = (unsigned)dst[e];
    if (d < (unsigned)N) atomicAdd(&deg[d], 1);
  }
}

__global__ __launch_bounds__(1024) void kScan(const int* __restrict__ deg, int* __restrict__ ptrA,
                                              int* __restrict__ cursor, int N){
  __shared__ int sWS[16];
  __shared__ int sWO[16];
  const int tid = threadIdx.x;
  const int C = (N + 1 + 1023) / 1024;
  const int i0 = tid * C;
  int local = 0;
  for (int i = i0; i < i0 + C && i < N; i++) local += deg[i];
  int lane = tid & 63, wv = tid >> 6;
  int v = local;
  #pragma unroll
  for (int d=1; d<64; d<<=1){ int u = __shfl_up(v, d); if (lane >= d) v += u; }
  if (lane == 63) sWS[wv] = v;
  __syncthreads();
  if (tid < 16){
    int s = sWS[tid];
    int vv = s;
    #pragma unroll
    for (int d=1; d<16; d<<=1){ int u = __shfl_up(vv, d); if (tid >= d) vv += u; }
    sWO[tid] = vv - s;
  }
  __syncthreads();
  int run = sWO[wv] + (v - local);
  for (int i = i0; i < i0 + C; i++){
    if (i <= N){
      ptrA[i] = run;
      if (i < N){ cursor[i] = run; run += deg[i]; }
    }
  }
}

__global__ void kFill(const int* __restrict__ dst, int* __restrict__ cursor,
                      int* __restrict__ csr, int E, int N){
  int e = blockIdx.x*256 + threadIdx.x;
  if (e < E){
    unsigned d = (unsigned)dst[e];
    if (d < (unsigned)N){ int p = atomicAdd(&cursor[d], 1); csr[p] = e; }
  }
}

// ---------------- GAT aggregation + elu + fc + relu ----------------
__global__ __launch_bounds__(256) void kAgg(const float* __restrict__ xl, const float* __restrict__ a_src,
    const float* __restrict__ a_dst, const int* __restrict__ esrc, const float* __restrict__ eattr,
    const int* __restrict__ ptrA, const int* __restrict__ csr, const float* __restrict__ cE,
    const float* __restrict__ eacc, const float* __restrict__ gat_bias, const float* __restrict__ fc_w,
    const float* __restrict__ fc_b, float* __restrict__ out, int N, int E)
{
  const int n = blockIdx.x*4 + (threadIdx.x >> 6);
  const int lane = threadIdx.x & 63;
  if (n >= N) return;
  float4 cEv = *(const float4*)cE;
  float eam = eacc[0] / (float)E;
  float4 ad  = *(const float4*)&a_dst[n*4];
  float4 asn = *(const float4*)&a_src[n*4];
  float sl0 = lrelu(asn.x + ad.x + eam*cEv.x);
  float sl1 = lrelu(asn.y + ad.y + eam*cEv.y);
  float sl2 = lrelu(asn.z + ad.z + eam*cEv.z);
  float sl3 = lrelu(asn.w + ad.w + eam*cEv.w);
  float mx0=sl0, mx1=sl1, mx2=sl2, mx3=sl3;
  const int p0 = ptrA[n], p1 = ptrA[n+1];
  for (int i = p0 + lane; i < p1; i += 64){
    int e = csr[i];
    int s = esrc[e];
    float ev = eattr[e];
    float4 av = *(const float4*)&a_src[s*4];
    mx0 = fmaxf(mx0, lrelu(av.x + ad.x + ev*cEv.x));
    mx1 = fmaxf(mx1, lrelu(av.y + ad.y + ev*cEv.y));
    mx2 = fmaxf(mx2, lrelu(av.z + ad.z + ev*cEv.z));
    mx3 = fmaxf(mx3, lrelu(av.w + ad.w + ev*cEv.w));
  }
  #pragma unroll
  for (int d=1; d<64; d<<=1){
    mx0 = fmaxf(mx0, __shfl_xor(mx0,d));
    mx1 = fmaxf(mx1, __shfl_xor(mx1,d));
    mx2 = fmaxf(mx2, __shfl_xor(mx2,d));
    mx3 = fmaxf(mx3, __shfl_xor(mx3,d));
  }
  const int ch0 = lane, ch1 = lane + 64;
  const int h0 = lane >> 5;
  float adh0 = h0 ? ad.y : ad.x,  adh1 = h0 ? ad.w : ad.z;
  float ceh0 = h0 ? cEv.y : cEv.x, ceh1 = h0 ? cEv.w : cEv.z;
  float mxh0 = h0 ? mx1 : mx0,    mxh1 = h0 ? mx3 : mx2;
  float slh0 = h0 ? sl1 : sl0,    slh1 = h0 ? sl3 : sl2;
  float pse0 = __expf(slh0 - mxh0), pse1 = __expf(slh1 - mxh1);
  float den0 = pse0, den1 = pse1;
  float acc0 = pse0 * xl[(size_t)n*128 + ch0];
  float acc1 = pse1 * xl[(size_t)n*128 + ch1];
  for (int i = p0; i < p1; i++){
    int e = csr[i];
    int s = esrc[e];
    float ev = eattr[e];
    float4 av = *(const float4*)&a_src[s*4];
    float avh0 = h0 ? av.y : av.x;
    float avh1 = h0 ? av.w : av.z;
    float pp0 = __expf(lrelu(avh0 + adh0 + ev*ceh0) - mxh0);
    float pp1 = __expf(lrelu(avh1 + adh1 + ev*ceh1) - mxh1);
    den0 += pp0; den1 += pp1;
    acc0 += pp0 * xl[(size_t)s*128 + ch0];
    acc1 += pp1 * xl[(size_t)s*128 + ch1];
  }
  float v0 = acc0/(den0 + 1e-16f) + gat_bias[ch0];
  float v1 = acc1/(den1 + 1e-16f) + gat_bias[ch1];
  v0 = v0 > 0.f ? v0 : __expf(v0) - 1.f;
  v1 = v1 > 0.f ? v1 : __expf(v1) - 1.f;
  #pragma unroll
  for (int o=0;o<4;o++){
    float p = fc_w[o*128 + ch0]*v0 + fc_w[o*128 + ch1]*v1;
    #pragma unroll
    for (int d=1; d<64; d<<=1) p += __shfl_xor(p, d);
    if (lane == 0) out[(size_t)n*4 + o] = fmaxf(p + fc_b[o], 0.f);
  }
}

extern "C" void kernel_launch(void* const* d_in, const int* in_sizes, int n_in,
                              void* d_out, int out_size, void* d_ws, size_t ws_size,
                              hipStream_t stream)
{
  (void)n_in; (void)out_size; (void)ws_size;
  const float* x          = (const float*)d_in[0];
  const int*   eidx       = (const int*)d_in[1];
  const float* eattr      = (const float*)d_in[2];
  const float* w_ih0      = (const float*)d_in[3];
  const float* w_hh0      = (const float*)d_in[4];
  const float* b_ih0      = (const float*)d_in[5];
  const float* b_hh0      = (const float*)d_in[6];
  const float* w_ih1      = (const float*)d_in[7];
  const float* w_hh1      = (const float*)d_in[8];
  const float* b_ih1      = (const float*)d_in[9];
  const float* b_hh1      = (const float*)d_in[10];
  const float* lin_w      = (const float*)d_in[11];
  const float* lin_edge_w = (const float*)d_in[12];
  const float* att_src    = (const float*)d_in[13];
  const float* att_dst    = (const float*)d_in[14];
  const float* att_edge   = (const float*)d_in[15];
  const float* gat_bias   = (const float*)d_in[16];
  const float* fc_w       = (const float*)d_in[17];
  const float* fc_b       = (const float*)d_in[18];
  float* out = (float*)d_out;

  const int N = in_sizes[0] / 32;
  const int E = in_sizes[1] / 2;
  const int* esrc = eidx;
  const int* edst = eidx + E;

  float* ws = (float*)d_ws;
  size_t o = 0;
  unsigned short* BfragHi = (unsigned short*)(ws + o); o += 24576;   // 49152 bf16
  unsigned short* BfragLo = (unsigned short*)(ws + o); o += 24576;
  float* linwT  = ws + o; o += 72*128;
  float* cE     = ws + o; o += 4;
  float* eacc   = ws + o; o += 4;
  float* h2last = ws + o; o += (size_t)N*64;
  float* xl     = ws + o; o += (size_t)N*128;
  float* a_src  = ws + o; o += (size_t)N*4;
  float* a_dst  = ws + o; o += (size_t)N*4;
  int* deg      = (int*)(ws + o); o += (size_t)N;
  int* ptrA     = (int*)(ws + o); o += (size_t)N + 1;
  int* cursor   = (int*)(ws + o); o += (size_t)N;
  int* csr      = (int*)(ws + o); o += (size_t)E;

  hipMemsetAsync(deg, 0, (size_t)N*4, stream);
  hipMemsetAsync(eacc, 0, 4, stream);
  kPrep<<<229, 256, 0, stream>>>(w_hh0, w_ih1, w_hh1, lin_w, lin_edge_w, att_edge,
                                 BfragHi, BfragLo, linwT, cE);
  kEa<<<512, 256, 0, stream>>>(eattr, eacc, E);
  kDeg<<<(E+255)/256, 256, 0, stream>>>(edst, deg, E, N);
  kScan<<<1, 1024, 0, stream>>>(deg, ptrA, cursor, N);
  kFill<<<(E+255)/256, 256, 0, stream>>>(edst, cursor, csr, E, N);

  kAB<<<(N+63)/64, 256, 0, stream>>>(x, BfragHi, BfragLo, w_ih0, b_ih0, b_hh0,
                                     b_ih1, b_hh1, h2last, N);

  kXL<<<(N+15)/16, 256, 0, stream>>>(h2last, x, linwT, att_src, att_dst, xl, a_src, a_dst, N);
  kAgg<<<(N+3)/4, 256, 0, stream>>>(xl, a_src, a_dst, esrc, eattr, ptrA, csr, cE, eacc,
                                    gat_bias, fc_w, fc_b, out, N, E);
}

// Round 8
// 1102.282 us; speedup vs baseline: 1.4298x; 1.4298x over previous
//
#include <hip/hip_runtime.h>
#include <cstdint>

#define TT 24

typedef short short8 __attribute__((ext_vector_type(8)));
typedef float f32x4 __attribute__((ext_vector_type(4)));

static __device__ __forceinline__ float fsig(float x){
  float e = __builtin_amdgcn_exp2f(-1.44269504f*x);
  return __builtin_amdgcn_rcpf(1.0f + e);
}
static __device__ __forceinline__ float ftanh(float x){
  float e = __builtin_amdgcn_exp2f(-2.88539008f*x);
  return fmaf(2.0f, __builtin_amdgcn_rcpf(1.0f + e), -1.0f);
}
static __device__ __forceinline__ float lrelu(float x){ return x > 0.f ? x : 0.2f*x; }

static __device__ __forceinline__ int swzh(int b){ return b ^ (((b>>7)&7)<<4); }
static __device__ __forceinline__ unsigned short f2bf(float f){
  unsigned u = __float_as_uint(f);
  u += 0x7FFF + ((u>>16)&1);
  return (unsigned short)(u>>16);
}
static __device__ __forceinline__ float bf2f(unsigned short h){
  return __uint_as_float(((unsigned)h)<<16);
}

// ---------------- prep: B-fragment build (split bf16) + linwT + cE ----------------
// Bhi/Blo[((mat*2+c)*16+tau)*512 + l*8 + j] = split of W[k=32c+8*(l>>4)+j][col=16*tau+(l&15)]
// where W[k][col] = wsrc[col*64+k]; mat 0=w_hh0, 1=w_ih1, 2=w_hh1. col = gate*64+jp.
__global__ void kPrep(const float* __restrict__ w_hh0, const float* __restrict__ w_ih1,
                      const float* __restrict__ w_hh1, const float* __restrict__ lin_w,
                      const float* __restrict__ lin_edge_w, const float* __restrict__ att_edge,
                      unsigned short* __restrict__ Bhi, unsigned short* __restrict__ Blo,
                      float* __restrict__ linwT, float* __restrict__ cE)
{
  int gid = blockIdx.x*256 + threadIdx.x;
  if (gid < 49152){
    int mat = gid / 16384;
    int r = gid - mat*16384;
    int c = r>>13, nt = (r>>9)&15, l = (r>>3)&63, j = r&7;
    int k = c*32 + (l>>4)*8 + j;
    int col = nt*16 + (l&15);
    const float* wsrc = (mat==0) ? w_hh0 : (mat==1 ? w_ih1 : w_hh1);
    float v = wsrc[col*64 + k];
    unsigned short hb = f2bf(v);
    unsigned short lb = f2bf(v - bf2f(hb));
    Bhi[gid] = hb;
    Blo[gid] = lb;
  }
  int g2 = gid - 49152;
  if (g2 >= 0 && g2 < 72*128){
    int k = g2 >> 7, ch = g2 & 127;
    linwT[g2] = lin_w[ch*72 + k];
  }
  if (gid >= 58368 && gid < 58372){
    int h = gid - 58368;
    float s = 0.f;
    for (int c=0;c<32;c++) s += lin_edge_w[h*32+c]*att_edge[h*32+c];
    cE[h] = s;
  }
}

// ---------------- fused 2-layer LSTM via MFMA, gate-major, in-register nonlin ----------------
// 32 nodes/block, 256 threads = 4 waves. Wave wv owns jp = wv*16+lr across ALL 4 gates
// (col = nt*64 + wv*16 + lr; fragment tau = nt*4 + wv). Nonlin fully in registers.
// h state in LDS as bf16 hi/lo, XOR-swizzled. 3 barriers/step. ~110-130 VGPR -> no spill
// (R7 lesson: 64-node variant spilled 2GB of scratch under a 128-reg cap).
// A/B k-slot convention (verified R6/R7): k = c*32 + (lane>>4)*8 + j for both operands.
// C/D: col=lane&15, row=(lane>>4)*4+reg (m89).
__global__ __launch_bounds__(256) void kAB(const float* __restrict__ x,
    const unsigned short* __restrict__ Bhi, const unsigned short* __restrict__ Blo,
    const float* __restrict__ w_ih0, const float* __restrict__ b_ih0, const float* __restrict__ b_hh0,
    const float* __restrict__ b_ih1, const float* __restrict__ b_hh1,
    float* __restrict__ h2last, int N)
{
  __shared__ __align__(16) unsigned short sH1h[2048];   // [32 node][64 jp] bf16-hi
  __shared__ __align__(16) unsigned short sH1l[2048];
  __shared__ __align__(16) unsigned short sH2h[2048];
  __shared__ __align__(16) unsigned short sH2l[2048];
  __shared__ float sX[32*25];                           // padded stride 25
  const int tid = threadIdx.x;
  const int wv = tid>>6, l = tid&63;
  const int lr = l&15, lg = l>>4;
  const int nb = blockIdx.x*32;

  for (int i=tid;i<32*24;i+=256){
    int m = i/24, tt = i - m*24;
    int n = nb + m;
    sX[m*25+tt] = (n<N) ? x[(size_t)n*32 + 8 + tt] : 0.f;
  }
  for (int i=tid;i<2048;i+=256){ sH1h[i]=0; sH1l[i]=0; sH2h[i]=0; sH2l[i]=0; }

  float wih[4], bb0[4], bb1[4];
  #pragma unroll
  for (int nt=0;nt<4;nt++){
    int col = nt*64 + wv*16 + lr;
    wih[nt] = w_ih0[col];
    bb0[nt] = b_ih0[col] + b_hh0[col];
    bb1[nt] = b_ih1[col] + b_hh1[col];
  }
  float cc0[8], cc1[8];
  #pragma unroll
  for (int i=0;i<8;i++){ cc0[i]=0.f; cc1[i]=0.f; }
  __syncthreads();

  const char* h1hB = (const char*)sH1h;
  const char* h1lB = (const char*)sH1l;
  const char* h2hB = (const char*)sH2h;
  const char* h2lB = (const char*)sH2l;

  for (int t=0;t<TT;t++){
    // ================= GEMM0: preact0 = h1(t-1)*W0 + x_t*wih + b  (in-reg) =================
    f32x4 acc[2][4];
    #pragma unroll
    for (int mt=0;mt<2;mt++){
      #pragma unroll
      for (int r=0;r<4;r++){
        float xv = sX[(mt*16 + lg*4 + r)*25 + t];
        #pragma unroll
        for (int nt=0;nt<4;nt++) acc[mt][nt][r] = fmaf(xv, wih[nt], bb0[nt]);
      }
    }
    #pragma unroll
    for (int c=0;c<2;c++){
      short8 aH[2], aL[2];
      #pragma unroll
      for (int mt=0;mt<2;mt++){
        int by = swzh((mt*16+lr)*128 + c*64 + lg*16);
        aH[mt] = *(const short8*)(h1hB + by);
        aL[mt] = *(const short8*)(h1lB + by);
      }
      #pragma unroll
      for (int nt=0;nt<4;nt++){
        int off = ((c*16 + nt*4 + wv)<<9) + l*8;
        short8 bH = *(const short8*)&Bhi[off];
        short8 bL = *(const short8*)&Blo[off];
        #pragma unroll
        for (int mt=0;mt<2;mt++){
          acc[mt][nt] = __builtin_amdgcn_mfma_f32_16x16x32_bf16(aH[mt], bH, acc[mt][nt], 0,0,0);
          acc[mt][nt] = __builtin_amdgcn_mfma_f32_16x16x32_bf16(aH[mt], bL, acc[mt][nt], 0,0,0);
          acc[mt][nt] = __builtin_amdgcn_mfma_f32_16x16x32_bf16(aL[mt], bH, acc[mt][nt], 0,0,0);
        }
      }
    }
    __syncthreads();   // B1: all waves done reading sH1(t-1)
    // ================= nonlin0 (in registers) -> write h1(t) =================
    #pragma unroll
    for (int mt=0;mt<2;mt++){
      #pragma unroll
      for (int r=0;r<4;r++){
        int idx = mt*4+r, nd = mt*16 + lg*4 + r;
        float ig = fsig(acc[mt][0][r]), fg = fsig(acc[mt][1][r]);
        float gg = ftanh(acc[mt][2][r]), og = fsig(acc[mt][3][r]);
        cc0[idx] = fg*cc0[idx] + ig*gg;
        float h = og*ftanh(cc0[idx]);
        unsigned u = __float_as_uint(h);
        unsigned short hb = (unsigned short)(u>>16);
        float d = h - __uint_as_float(u & 0xFFFF0000u);
        unsigned short lb = (unsigned short)(__float_as_uint(d)>>16);
        int by = swzh(nd*128 + (wv*16+lr)*2);
        *(unsigned short*)((char*)sH1h + by) = hb;
        *(unsigned short*)((char*)sH1l + by) = lb;
      }
    }
    __syncthreads();   // B2: h1(t) visible
    // ================= GEMM1: preact1 = [h1(t);h2(t-1)] * [Wih1;Whh1] + b =================
    #pragma unroll
    for (int mt=0;mt<2;mt++)
      #pragma unroll
      for (int nt=0;nt<4;nt++)
        #pragma unroll
        for (int r=0;r<4;r++) acc[mt][nt][r] = bb1[nt];
    #pragma unroll
    for (int c4=0;c4<4;c4++){
      const char* srcH = (c4<2) ? h1hB : h2hB;
      const char* srcL = (c4<2) ? h1lB : h2lB;
      int cc = c4&1;
      int matB = (c4<2) ? 32 : 64;
      short8 aH[2], aL[2];
      #pragma unroll
      for (int mt=0;mt<2;mt++){
        int by = swzh((mt*16+lr)*128 + cc*64 + lg*16);
        aH[mt] = *(const short8*)(srcH + by);
        aL[mt] = *(const short8*)(srcL + by);
      }
      #pragma unroll
      for (int nt=0;nt<4;nt++){
        int off = ((matB + cc*16 + nt*4 + wv)<<9) + l*8;
        short8 bH = *(const short8*)&Bhi[off];
        short8 bL = *(const short8*)&Blo[off];
        #pragma unroll
        for (int mt=0;mt<2;mt++){
          acc[mt][nt] = __builtin_amdgcn_mfma_f32_16x16x32_bf16(aH[mt], bH, acc[mt][nt], 0,0,0);
          acc[mt][nt] = __builtin_amdgcn_mfma_f32_16x16x32_bf16(aH[mt], bL, acc[mt][nt], 0,0,0);
          acc[mt][nt] = __builtin_amdgcn_mfma_f32_16x16x32_bf16(aL[mt], bH, acc[mt][nt], 0,0,0);
        }
      }
    }
    __syncthreads();   // B3: all waves done reading sH2(t-1)
    // ================= nonlin1 (in registers) -> write h2(t) =================
    #pragma unroll
    for (int mt=0;mt<2;mt++){
      #pragma unroll
      for (int r=0;r<4;r++){
        int idx = mt*4+r, nd = mt*16 + lg*4 + r;
        float ig = fsig(acc[mt][0][r]), fg = fsig(acc[mt][1][r]);
        float gg = ftanh(acc[mt][2][r]), og = fsig(acc[mt][3][r]);
        cc1[idx] = fg*cc1[idx] + ig*gg;
        float h = og*ftanh(cc1[idx]);
        unsigned u = __float_as_uint(h);
        unsigned short hb = (unsigned short)(u>>16);
        float d = h - __uint_as_float(u & 0xFFFF0000u);
        unsigned short lb = (unsigned short)(__float_as_uint(d)>>16);
        int by = swzh(nd*128 + (wv*16+lr)*2);
        *(unsigned short*)((char*)sH2h + by) = hb;
        *(unsigned short*)((char*)sH2l + by) = lb;
        if (t == TT-1){
          int n = nb + nd;
          if (n < N) h2last[(size_t)n*64 + wv*16 + lr] = h;
        }
      }
    }
    // no 4th barrier: sH2(t) writes are separated from G1(t+1) reads by B1+B2 of t+1,
    // and G0(t+1) touches only sH1.
  }
}

// ---------------- GAT linear + attention coefficients ----------------
__global__ __launch_bounds__(256) void kXL(const float* __restrict__ h2last, const float* __restrict__ x,
    const float* __restrict__ linwT, const float* __restrict__ att_src, const float* __restrict__ att_dst,
    float* __restrict__ xl, float* __restrict__ a_src, float* __restrict__ a_dst, int N)
{
  __shared__ float sLW[72*128];
  __shared__ float sC[16*72];
  const int tid = threadIdx.x;
  const int nb0 = blockIdx.x * 16;
  for (int i = tid*4; i < 9216; i += 1024)
    *(float4*)&sLW[i] = *(const float4*)&linwT[i];
  for (int i = tid; i < 16*64; i += 256){
    int m = i >> 6, k = i & 63; int n = nb0 + m;
    sC[m*72 + k] = (n < N) ? h2last[(size_t)n*64 + k] : 0.f;
  }
  if (tid < 128){
    int m = tid >> 3, j = tid & 7; int n = nb0 + m;
    sC[m*72 + 64 + j] = (n < N) ? x[(size_t)n*32 + j] : 0.f;
  }
  __syncthreads();
  const int ch = tid & 127, half = tid >> 7;
  float acc[8];
  #pragma unroll
  for (int m=0;m<8;m++) acc[m]=0.f;
  for (int k=0;k<72;k++){
    float w = sLW[k*128 + ch];
    #pragma unroll
    for (int m=0;m<8;m++) acc[m] += w * sC[(half*8+m)*72 + k];
  }
  float aS = att_src[ch], aD = att_dst[ch];
  int h = ch >> 5;
  #pragma unroll
  for (int m=0;m<8;m++){
    int n = nb0 + half*8 + m;
    float v = acc[m];
    float ps = v*aS, pd = v*aD;
    #pragma unroll
    for (int d=1; d<32; d<<=1){ ps += __shfl_xor(ps, d); pd += __shfl_xor(pd, d); }
    if (n < N){
      xl[(size_t)n*128 + ch] = v;
      if ((ch & 31) == 0){ a_src[n*4 + h] = ps; a_dst[n*4 + h] = pd; }
    }
  }
}

// ---------------- edge_attr mean ----------------
__global__ void kEa(const float* __restrict__ ea, float* __restrict__ acc, int E){
  int gid = blockIdx.x*blockDim.x + threadIdx.x;
  float s = 0.f;
  for (int i = gid; i < E; i += gridDim.x*blockDim.x) s += ea[i];
  #pragma unroll
  for (int d=1; d<64; d<<=1) s += __shfl_xor(s, d);
  if ((threadIdx.x & 63) == 0) atomicAdd(acc, s);
}

// ---------------- CSR build (edge_index is int32 per harness spec) ----------------
__global__ void kDeg(const int* __restrict__ dst, int* __restrict__ deg, int E, int N){
  int e = blockIdx.x*256 + threadIdx.x;
  if (e < E){
    unsigned d = (unsigned)dst[e];
    if (d < (unsigned)N) atomicAdd(&deg[d], 1);
  }
}

__global__ __launch_bounds__(1024) void kScan(const int* __restrict__ deg, int* __restrict__ ptrA,
                                              int* __restrict__ cursor, int N){
  __shared__ int sWS[16];
  __shared__ int sWO[16];
  const int tid = threadIdx.x;
  const int C = (N + 1 + 1023) / 1024;
  const int i0 = tid * C;
  int local = 0;
  for (int i = i0; i < i0 + C && i < N; i++) local += deg[i];
  int lane = tid & 63, wv = tid >> 6;
  int v = local;
  #pragma unroll
  for (int d=1; d<64; d<<=1){ int u = __shfl_up(v, d); if (lane >= d) v += u; }
  if (lane == 63) sWS[wv] = v;
  __syncthreads();
  if (tid < 16){
    int s = sWS[tid];
    int vv = s;
    #pragma unroll
    for (int d=1; d<16; d<<=1){ int u = __shfl_up(vv, d); if (tid >= d) vv += u; }
    sWO[tid] = vv - s;
  }
  __syncthreads();
  int run = sWO[wv] + (v - local);
  for (int i = i0; i < i0 + C; i++){
    if (i <= N){
      ptrA[i] = run;
      if (i < N){ cursor[i] = run; run += deg[i]; }
    }
  }
}

__global__ void kFill(const int* __restrict__ dst, int* __restrict__ cursor,
                      int* __restrict__ csr, int E, int N){
  int e = blockIdx.x*256 + threadIdx.x;
  if (e < E){
    unsigned d = (unsigned)dst[e];
    if (d < (unsigned)N){ int p = atomicAdd(&cursor[d], 1); csr[p] = e; }
  }
}

// ---------------- GAT aggregation + elu + fc + relu ----------------
__global__ __launch_bounds__(256) void kAgg(const float* __restrict__ xl, const float* __restrict__ a_src,
    const float* __restrict__ a_dst, const int* __restrict__ esrc, const float* __restrict__ eattr,
    const int* __restrict__ ptrA, const int* __restrict__ csr, const float* __restrict__ cE,
    const float* __restrict__ eacc, const float* __restrict__ gat_bias, const float* __restrict__ fc_w,
    const float* __restrict__ fc_b, float* __restrict__ out, int N, int E)
{
  const int n = blockIdx.x*4 + (threadIdx.x >> 6);
  const int lane = threadIdx.x & 63;
  if (n >= N) return;
  float4 cEv = *(const float4*)cE;
  float eam = eacc[0] / (float)E;
  float4 ad  = *(const float4*)&a_dst[n*4];
  float4 asn = *(const float4*)&a_src[n*4];
  float sl0 = lrelu(asn.x + ad.x + eam*cEv.x);
  float sl1 = lrelu(asn.y + ad.y + eam*cEv.y);
  float sl2 = lrelu(asn.z + ad.z + eam*cEv.z);
  float sl3 = lrelu(asn.w + ad.w + eam*cEv.w);
  float mx0=sl0, mx1=sl1, mx2=sl2, mx3=sl3;
  const int p0 = ptrA[n], p1 = ptrA[n+1];
  for (int i = p0 + lane; i < p1; i += 64){
    int e = csr[i];
    int s = esrc[e];
    float ev = eattr[e];
    float4 av = *(const float4*)&a_src[s*4];
    mx0 = fmaxf(mx0, lrelu(av.x + ad.x + ev*cEv.x));
    mx1 = fmaxf(mx1, lrelu(av.y + ad.y + ev*cEv.y));
    mx2 = fmaxf(mx2, lrelu(av.z + ad.z + ev*cEv.z));
    mx3 = fmaxf(mx3, lrelu(av.w + ad.w + ev*cEv.w));
  }
  #pragma unroll
  for (int d=1; d<64; d<<=1){
    mx0 = fmaxf(mx0, __shfl_xor(mx0,d));
    mx1 = fmaxf(mx1, __shfl_xor(mx1,d));
    mx2 = fmaxf(mx2, __shfl_xor(mx2,d));
    mx3 = fmaxf(mx3, __shfl_xor(mx3,d));
  }
  const int ch0 = lane, ch1 = lane + 64;
  const int h0 = lane >> 5;
  float adh0 = h0 ? ad.y : ad.x,  adh1 = h0 ? ad.w : ad.z;
  float ceh0 = h0 ? cEv.y : cEv.x, ceh1 = h0 ? cEv.w : cEv.z;
  float mxh0 = h0 ? mx1 : mx0,    mxh1 = h0 ? mx3 : mx2;
  float slh0 = h0 ? sl1 : sl0,    slh1 = h0 ? sl3 : sl2;
  float pse0 = __expf(slh0 - mxh0), pse1 = __expf(slh1 - mxh1);
  float den0 = pse0, den1 = pse1;
  float acc0 = pse0 * xl[(size_t)n*128 + ch0];
  float acc1 = pse1 * xl[(size_t)n*128 + ch1];
  for (int i = p0; i < p1; i++){
    int e = csr[i];
    int s = esrc[e];
    float ev = eattr[e];
    float4 av = *(const float4*)&a_src[s*4];
    float avh0 = h0 ? av.y : av.x;
    float avh1 = h0 ? av.w : av.z;
    float pp0 = __expf(lrelu(avh0 + adh0 + ev*ceh0) - mxh0);
    float pp1 = __expf(lrelu(avh1 + adh1 + ev*ceh1) - mxh1);
    den0 += pp0; den1 += pp1;
    acc0 += pp0 * xl[(size_t)s*128 + ch0];
    acc1 += pp1 * xl[(size_t)s*128 + ch1];
  }
  float v0 = acc0/(den0 + 1e-16f) + gat_bias[ch0];
  float v1 = acc1/(den1 + 1e-16f) + gat_bias[ch1];
  v0 = v0 > 0.f ? v0 : __expf(v0) - 1.f;
  v1 = v1 > 0.f ? v1 : __expf(v1) - 1.f;
  #pragma unroll
  for (int o=0;o<4;o++){
    float p = fc_w[o*128 + ch0]*v0 + fc_w[o*128 + ch1]*v1;
    #pragma unroll
    for (int d=1; d<64; d<<=1) p += __shfl_xor(p, d);
    if (lane == 0) out[(size_t)n*4 + o] = fmaxf(p + fc_b[o], 0.f);
  }
}

extern "C" void kernel_launch(void* const* d_in, const int* in_sizes, int n_in,
                              void* d_out, int out_size, void* d_ws, size_t ws_size,
                              hipStream_t stream)
{
  (void)n_in; (void)out_size; (void)ws_size;
  const float* x          = (const float*)d_in[0];
  const int*   eidx       = (const int*)d_in[1];
  const float* eattr      = (const float*)d_in[2];
  const float* w_ih0      = (const float*)d_in[3];
  const float* w_hh0      = (const float*)d_in[4];
  const float* b_ih0      = (const float*)d_in[5];
  const float* b_hh0      = (const float*)d_in[6];
  const float* w_ih1      = (const float*)d_in[7];
  const float* w_hh1      = (const float*)d_in[8];
  const float* b_ih1      = (const float*)d_in[9];
  const float* b_hh1      = (const float*)d_in[10];
  const float* lin_w      = (const float*)d_in[11];
  const float* lin_edge_w = (const float*)d_in[12];
  const float* att_src    = (const float*)d_in[13];
  const float* att_dst    = (const float*)d_in[14];
  const float* att_edge   = (const float*)d_in[15];
  const float* gat_bias   = (const float*)d_in[16];
  const float* fc_w       = (const float*)d_in[17];
  const float* fc_b       = (const float*)d_in[18];
  float* out = (float*)d_out;

  const int N = in_sizes[0] / 32;
  const int E = in_sizes[1] / 2;
  const int* esrc = eidx;
  const int* edst = eidx + E;

  float* ws = (float*)d_ws;
  size_t o = 0;
  unsigned short* BfragHi = (unsigned short*)(ws + o); o += 24576;   // 49152 bf16
  unsigned short* BfragLo = (unsigned short*)(ws + o); o += 24576;
  float* linwT  = ws + o; o += 72*128;
  float* cE     = ws + o; o += 4;
  float* eacc   = ws + o; o += 4;
  float* h2last = ws + o; o += (size_t)N*64;
  float* xl     = ws + o; o += (size_t)N*128;
  float* a_src  = ws + o; o += (size_t)N*4;
  float* a_dst  = ws + o; o += (size_t)N*4;
  int* deg      = (int*)(ws + o); o += (size_t)N;
  int* ptrA     = (int*)(ws + o); o += (size_t)N + 1;
  int* cursor   = (int*)(ws + o); o += (size_t)N;
  int* csr      = (int*)(ws + o); o += (size_t)E;

  hipMemsetAsync(deg, 0, (size_t)N*4, stream);
  hipMemsetAsync(eacc, 0, 4, stream);
  kPrep<<<229, 256, 0, stream>>>(w_hh0, w_ih1, w_hh1, lin_w, lin_edge_w, att_edge,
                                 BfragHi, BfragLo, linwT, cE);
  kEa<<<512, 256, 0, stream>>>(eattr, eacc, E);
  kDeg<<<(E+255)/256, 256, 0, stream>>>(edst, deg, E, N);
  kScan<<<1, 1024, 0, stream>>>(deg, ptrA, cursor, N);
  kFill<<<(E+255)/256, 256, 0, stream>>>(edst, cursor, csr, E, N);

  kAB<<<(N+31)/32, 256, 0, stream>>>(x, BfragHi, BfragLo, w_ih0, b_ih0, b_hh0,
                                     b_ih1, b_hh1, h2last, N);

  kXL<<<(N+15)/16, 256, 0, stream>>>(h2last, x, linwT, att_src, att_dst, xl, a_src, a_dst, N);
  kAgg<<<(N+3)/4, 256, 0, stream>>>(xl, a_src, a_dst, esrc, eattr, ptrA, csr, cE, eacc,
                                    gat_bias, fc_w, fc_b, out, N, E);
}

// Round 9
// 844.566 us; speedup vs baseline: 1.8661x; 1.3051x over previous
//
#include <hip/hip_runtime.h>
#include <cstdint>

#define TT 24

typedef _Float16 half8 __attribute__((ext_vector_type(8)));
typedef float f32x4 __attribute__((ext_vector_type(4)));

static __device__ __forceinline__ float fsig(float x){
  float e = __builtin_amdgcn_exp2f(-1.44269504f*x);
  return __builtin_amdgcn_rcpf(1.0f + e);
}
static __device__ __forceinline__ float ftanh(float x){
  float e = __builtin_amdgcn_exp2f(-2.88539008f*x);
  return fmaf(2.0f, __builtin_amdgcn_rcpf(1.0f + e), -1.0f);
}
static __device__ __forceinline__ float lrelu(float x){ return x > 0.f ? x : 0.2f*x; }

static __device__ __forceinline__ int swzh(int b){ return b ^ (((b>>7)&7)<<4); }

// ---------------- prep: B-fragment build (fp16 single-plane) + linwT + cE ----------------
// Bf[((mat*2+c)*16+tau)*512 + l*8 + j] = fp16( W[k=32c+8*(l>>4)+j][col=16*tau+(l&15)] )
// where W[k][col] = wsrc[col*64+k]; mat 0=w_hh0, 1=w_ih1, 2=w_hh1. col = gate*64+jp.
__global__ void kPrep(const float* __restrict__ w_hh0, const float* __restrict__ w_ih1,
                      const float* __restrict__ w_hh1, const float* __restrict__ lin_w,
                      const float* __restrict__ lin_edge_w, const float* __restrict__ att_edge,
                      unsigned short* __restrict__ Bf,
                      float* __restrict__ linwT, float* __restrict__ cE)
{
  int gid = blockIdx.x*256 + threadIdx.x;
  if (gid < 49152){
    int mat = gid / 16384;
    int r = gid - mat*16384;
    int c = r>>13, nt = (r>>9)&15, l = (r>>3)&63, j = r&7;
    int k = c*32 + (l>>4)*8 + j;
    int col = nt*16 + (l&15);
    const float* wsrc = (mat==0) ? w_hh0 : (mat==1 ? w_ih1 : w_hh1);
    float v = wsrc[col*64 + k];
    union { _Float16 f; unsigned short u; } cv;
    cv.f = (_Float16)v;
    Bf[gid] = cv.u;
  }
  int g2 = gid - 49152;
  if (g2 >= 0 && g2 < 72*128){
    int k = g2 >> 7, ch = g2 & 127;
    linwT[g2] = lin_w[ch*72 + k];
  }
  if (gid >= 58368 && gid < 58372){
    int h = gid - 58368;
    float s = 0.f;
    for (int c=0;c<32;c++) s += lin_edge_w[h*32+c]*att_edge[h*32+c];
    cE[h] = s;
  }
}

// ---------------- fused 2-layer LSTM via fp16 MFMA, all weights LDS-resident ----------------
// 64 nodes/block, 512 threads = 8 waves (wq = wid&3 owns taus nt*4+wq across all 4 gates;
// wm = wid>>2 owns node half). ALL weight fragments staged to LDS once (96 KB) -> zero
// global weight traffic in t-loop (R8 lesson: 192KB/block-step L2 streaming was the wall).
// fp16 single product (no hi/lo split): 1 MFMA per fragment pair, h stored fp16.
// Nonlin fully in registers (gate-major). 3 barriers/step.
// A/B k-slot convention (verified R6-R8): k = c*32 + (lane>>4)*8 + j for both operands.
// C/D: col=lane&15, row=(lane>>4)*4+reg (m89).
__global__ __launch_bounds__(512) void kAB(const float* __restrict__ x,
    const unsigned short* __restrict__ Bf,
    const float* __restrict__ w_ih0, const float* __restrict__ b_ih0, const float* __restrict__ b_hh0,
    const float* __restrict__ b_ih1, const float* __restrict__ b_hh1,
    float* __restrict__ h2last, int N)
{
  __shared__ __align__(16) unsigned short sB[49152];   // 96 KB: all weight fragments
  __shared__ __align__(16) unsigned short sH1[4096];   // [64 node][64 jp] fp16, swizzled
  __shared__ __align__(16) unsigned short sH2[4096];
  __shared__ float sX[64*25];                          // padded stride 25
  const int tid = threadIdx.x;
  const int wid = tid>>6, l = tid&63;
  const int wq = wid&3, wm = wid>>2;
  const int lr = l&15, lg = l>>4;
  const int nb = blockIdx.x*64;

  for (int i=tid; i<6144; i+=512)
    ((uint4*)sB)[i] = ((const uint4*)Bf)[i];
  for (int i=tid;i<1536;i+=512){
    int m = i/24, tt = i - m*24;
    int n = nb + m;
    sX[m*25+tt] = (n<N) ? x[(size_t)n*32 + 8 + tt] : 0.f;
  }
  for (int i=tid;i<4096;i+=512){ sH1[i]=0; sH2[i]=0; }

  float wih[4], bb0[4], bb1[4];
  #pragma unroll
  for (int nt=0;nt<4;nt++){
    int col = nt*64 + wq*16 + lr;
    wih[nt] = w_ih0[col];
    bb0[nt] = b_ih0[col] + b_hh0[col];
    bb1[nt] = b_ih1[col] + b_hh1[col];
  }
  float cc0[8], cc1[8];
  #pragma unroll
  for (int i=0;i<8;i++){ cc0[i]=0.f; cc1[i]=0.f; }
  __syncthreads();

  const char* h1B = (const char*)sH1;
  const char* h2B = (const char*)sH2;

  for (int t=0;t<TT;t++){
    // ========== GEMM0: preact0 = h1(t-1)*W0 + x_t*wih + b  (in-reg acc) ==========
    f32x4 acc[2][4];
    #pragma unroll
    for (int mt=0;mt<2;mt++){
      #pragma unroll
      for (int r=0;r<4;r++){
        float xv = sX[(wm*32 + mt*16 + lg*4 + r)*25 + t];
        #pragma unroll
        for (int nt=0;nt<4;nt++) acc[mt][nt][r] = fmaf(xv, wih[nt], bb0[nt]);
      }
    }
    #pragma unroll
    for (int c=0;c<2;c++){
      half8 a[2];
      #pragma unroll
      for (int mt=0;mt<2;mt++){
        int by = swzh((wm*32 + mt*16 + lr)*128 + c*64 + lg*16);
        a[mt] = *(const half8*)(h1B + by);
      }
      #pragma unroll
      for (int nt=0;nt<4;nt++){
        half8 b = *(const half8*)&sB[((c*16 + nt*4 + wq)<<9) + l*8];
        #pragma unroll
        for (int mt=0;mt<2;mt++)
          acc[mt][nt] = __builtin_amdgcn_mfma_f32_16x16x32_f16(a[mt], b, acc[mt][nt], 0,0,0);
      }
    }
    __syncthreads();   // B1: all waves done reading sH1(t-1)
    // ========== nonlin0 (registers) -> write h1(t) fp16 ==========
    #pragma unroll
    for (int mt=0;mt<2;mt++){
      #pragma unroll
      for (int r=0;r<4;r++){
        int idx = mt*4+r, nd = wm*32 + mt*16 + lg*4 + r;
        float ig = fsig(acc[mt][0][r]), fg = fsig(acc[mt][1][r]);
        float gg = ftanh(acc[mt][2][r]), og = fsig(acc[mt][3][r]);
        cc0[idx] = fg*cc0[idx] + ig*gg;
        float h = og*ftanh(cc0[idx]);
        union { _Float16 f; unsigned short u; } cv; cv.f = (_Float16)h;
        *(unsigned short*)((char*)sH1 + swzh(nd*128 + (wq*16+lr)*2)) = cv.u;
      }
    }
    __syncthreads();   // B2: h1(t) visible
    // ========== GEMM1: preact1 = [h1(t);h2(t-1)] * [Wih1;Whh1] + b ==========
    #pragma unroll
    for (int mt=0;mt<2;mt++)
      #pragma unroll
      for (int nt=0;nt<4;nt++)
        #pragma unroll
        for (int r=0;r<4;r++) acc[mt][nt][r] = bb1[nt];
    #pragma unroll
    for (int c4=0;c4<4;c4++){
      const char* srcA = (c4<2) ? h1B : h2B;
      int cc = c4&1;
      int matB = (c4<2) ? 32 : 64;
      half8 a[2];
      #pragma unroll
      for (int mt=0;mt<2;mt++){
        int by = swzh((wm*32 + mt*16 + lr)*128 + cc*64 + lg*16);
        a[mt] = *(const half8*)(srcA + by);
      }
      #pragma unroll
      for (int nt=0;nt<4;nt++){
        half8 b = *(const half8*)&sB[((matB + cc*16 + nt*4 + wq)<<9) + l*8];
        #pragma unroll
        for (int mt=0;mt<2;mt++)
          acc[mt][nt] = __builtin_amdgcn_mfma_f32_16x16x32_f16(a[mt], b, acc[mt][nt], 0,0,0);
      }
    }
    __syncthreads();   // B3: all waves done reading sH2(t-1)
    // ========== nonlin1 (registers) -> write h2(t) fp16; fp32 out at t=23 ==========
    #pragma unroll
    for (int mt=0;mt<2;mt++){
      #pragma unroll
      for (int r=0;r<4;r++){
        int idx = mt*4+r, nd = wm*32 + mt*16 + lg*4 + r;
        float ig = fsig(acc[mt][0][r]), fg = fsig(acc[mt][1][r]);
        float gg = ftanh(acc[mt][2][r]), og = fsig(acc[mt][3][r]);
        cc1[idx] = fg*cc1[idx] + ig*gg;
        float h = og*ftanh(cc1[idx]);
        union { _Float16 f; unsigned short u; } cv; cv.f = (_Float16)h;
        *(unsigned short*)((char*)sH2 + swzh(nd*128 + (wq*16+lr)*2)) = cv.u;
        if (t == TT-1){
          int n = nb + nd;
          if (n < N) h2last[(size_t)n*64 + wq*16 + lr] = h;
        }
      }
    }
    // no 4th barrier: sH2(t) writes vs G1(t+1) reads are separated by B1+B2 of t+1;
    // G0(t+1) touches only sH1.
  }
}

// ---------------- GAT linear + attention coefficients ----------------
__global__ __launch_bounds__(256) void kXL(const float* __restrict__ h2last, const float* __restrict__ x,
    const float* __restrict__ linwT, const float* __restrict__ att_src, const float* __restrict__ att_dst,
    float* __restrict__ xl, float* __restrict__ a_src, float* __restrict__ a_dst, int N)
{
  __shared__ float sLW[72*128];
  __shared__ float sC[16*72];
  const int tid = threadIdx.x;
  const int nb0 = blockIdx.x * 16;
  for (int i = tid*4; i < 9216; i += 1024)
    *(float4*)&sLW[i] = *(const float4*)&linwT[i];
  for (int i = tid; i < 16*64; i += 256){
    int m = i >> 6, k = i & 63; int n = nb0 + m;
    sC[m*72 + k] = (n < N) ? h2last[(size_t)n*64 + k] : 0.f;
  }
  if (tid < 128){
    int m = tid >> 3, j = tid & 7; int n = nb0 + m;
    sC[m*72 + 64 + j] = (n < N) ? x[(size_t)n*32 + j] : 0.f;
  }
  __syncthreads();
  const int ch = tid & 127, half = tid >> 7;
  float acc[8];
  #pragma unroll
  for (int m=0;m<8;m++) acc[m]=0.f;
  for (int k=0;k<72;k++){
    float w = sLW[k*128 + ch];
    #pragma unroll
    for (int m=0;m<8;m++) acc[m] += w * sC[(half*8+m)*72 + k];
  }
  float aS = att_src[ch], aD = att_dst[ch];
  int h = ch >> 5;
  #pragma unroll
  for (int m=0;m<8;m++){
    int n = nb0 + half*8 + m;
    float v = acc[m];
    float ps = v*aS, pd = v*aD;
    #pragma unroll
    for (int d=1; d<32; d<<=1){ ps += __shfl_xor(ps, d); pd += __shfl_xor(pd, d); }
    if (n < N){
      xl[(size_t)n*128 + ch] = v;
      if ((ch & 31) == 0){ a_src[n*4 + h] = ps; a_dst[n*4 + h] = pd; }
    }
  }
}

// ---------------- edge_attr mean ----------------
__global__ void kEa(const float* __restrict__ ea, float* __restrict__ acc, int E){
  int gid = blockIdx.x*blockDim.x + threadIdx.x;
  float s = 0.f;
  for (int i = gid; i < E; i += gridDim.x*blockDim.x) s += ea[i];
  #pragma unroll
  for (int d=1; d<64; d<<=1) s += __shfl_xor(s, d);
  if ((threadIdx.x & 63) == 0) atomicAdd(acc, s);
}

// ---------------- CSR build (edge_index is int32 per harness spec) ----------------
__global__ void kDeg(const int* __restrict__ dst, int* __restrict__ deg, int E, int N){
  int e = blockIdx.x*256 + threadIdx.x;
  if (e < E){
    unsigned d = (unsigned)dst[e];
    if (d < (unsigned)N) atomicAdd(&deg[d], 1);
  }
}

__global__ __launch_bounds__(1024) void kScan(const int* __restrict__ deg, int* __restrict__ ptrA,
                                              int* __restrict__ cursor, int N){
  __shared__ int sWS[16];
  __shared__ int sWO[16];
  const int tid = threadIdx.x;
  const int C = (N + 1 + 1023) / 1024;
  const int i0 = tid * C;
  int local = 0;
  for (int i = i0; i < i0 + C && i < N; i++) local += deg[i];
  int lane = tid & 63, wv = tid >> 6;
  int v = local;
  #pragma unroll
  for (int d=1; d<64; d<<=1){ int u = __shfl_up(v, d); if (lane >= d) v += u; }
  if (lane == 63) sWS[wv] = v;
  __syncthreads();
  if (tid < 16){
    int s = sWS[tid];
    int vv = s;
    #pragma unroll
    for (int d=1; d<16; d<<=1){ int u = __shfl_up(vv, d); if (tid >= d) vv += u; }
    sWO[tid] = vv - s;
  }
  __syncthreads();
  int run = sWO[wv] + (v - local);
  for (int i = i0; i < i0 + C; i++){
    if (i <= N){
      ptrA[i] = run;
      if (i < N){ cursor[i] = run; run += deg[i]; }
    }
  }
}

__global__ void kFill(const int* __restrict__ dst, int* __restrict__ cursor,
                      int* __restrict__ csr, int E, int N){
  int e = blockIdx.x*256 + threadIdx.x;
  if (e < E){
    unsigned d = (unsigned)dst[e];
    if (d < (unsigned)N){ int p = atomicAdd(&cursor[d], 1); csr[p] = e; }
  }
}

// ---------------- GAT aggregation + elu + fc + relu ----------------
__global__ __launch_bounds__(256) void kAgg(const float* __restrict__ xl, const float* __restrict__ a_src,
    const float* __restrict__ a_dst, const int* __restrict__ esrc, const float* __restrict__ eattr,
    const int* __restrict__ ptrA, const int* __restrict__ csr, const float* __restrict__ cE,
    const float* __restrict__ eacc, const float* __restrict__ gat_bias, const float* __restrict__ fc_w,
    const float* __restrict__ fc_b, float* __restrict__ out, int N, int E)
{
  const int n = blockIdx.x*4 + (threadIdx.x >> 6);
  const int lane = threadIdx.x & 63;
  if (n >= N) return;
  float4 cEv = *(const float4*)cE;
  float eam = eacc[0] / (float)E;
  float4 ad  = *(const float4*)&a_dst[n*4];
  float4 asn = *(const float4*)&a_src[n*4];
  float sl0 = lrelu(asn.x + ad.x + eam*cEv.x);
  float sl1 = lrelu(asn.y + ad.y + eam*cEv.y);
  float sl2 = lrelu(asn.z + ad.z + eam*cEv.z);
  float sl3 = lrelu(asn.w + ad.w + eam*cEv.w);
  float mx0=sl0, mx1=sl1, mx2=sl2, mx3=sl3;
  const int p0 = ptrA[n], p1 = ptrA[n+1];
  for (int i = p0 + lane; i < p1; i += 64){
    int e = csr[i];
    int s = esrc[e];
    float ev = eattr[e];
    float4 av = *(const float4*)&a_src[s*4];
    mx0 = fmaxf(mx0, lrelu(av.x + ad.x + ev*cEv.x));
    mx1 = fmaxf(mx1, lrelu(av.y + ad.y + ev*cEv.y));
    mx2 = fmaxf(mx2, lrelu(av.z + ad.z + ev*cEv.z));
    mx3 = fmaxf(mx3, lrelu(av.w + ad.w + ev*cEv.w));
  }
  #pragma unroll
  for (int d=1; d<64; d<<=1){
    mx0 = fmaxf(mx0, __shfl_xor(mx0,d));
    mx1 = fmaxf(mx1, __shfl_xor(mx1,d));
    mx2 = fmaxf(mx2, __shfl_xor(mx2,d));
    mx3 = fmaxf(mx3, __shfl_xor(mx3,d));
  }
  const int ch0 = lane, ch1 = lane + 64;
  const int h0 = lane >> 5;
  float adh0 = h0 ? ad.y : ad.x,  adh1 = h0 ? ad.w : ad.z;
  float ceh0 = h0 ? cEv.y : cEv.x, ceh1 = h0 ? cEv.w : cEv.z;
  float mxh0 = h0 ? mx1 : mx0,    mxh1 = h0 ? mx3 : mx2;
  float slh0 = h0 ? sl1 : sl0,    slh1 = h0 ? sl3 : sl2;
  float pse0 = __expf(slh0 - mxh0), pse1 = __expf(slh1 - mxh1);
  float den0 = pse0, den1 = pse1;
  float acc0 = pse0 * xl[(size_t)n*128 + ch0];
  float acc1 = pse1 * xl[(size_t)n*128 + ch1];
  for (int i = p0; i < p1; i++){
    int e = csr[i];
    int s = esrc[e];
    float ev = eattr[e];
    float4 av = *(const float4*)&a_src[s*4];
    float avh0 = h0 ? av.y : av.x;
    float avh1 = h0 ? av.w : av.z;
    float pp0 = __expf(lrelu(avh0 + adh0 + ev*ceh0) - mxh0);
    float pp1 = __expf(lrelu(avh1 + adh1 + ev*ceh1) - mxh1);
    den0 += pp0; den1 += pp1;
    acc0 += pp0 * xl[(size_t)s*128 + ch0];
    acc1 += pp1 * xl[(size_t)s*128 + ch1];
  }
  float v0 = acc0/(den0 + 1e-16f) + gat_bias[ch0];
  float v1 = acc1/(den1 + 1e-16f) + gat_bias[ch1];
  v0 = v0 > 0.f ? v0 : __expf(v0) - 1.f;
  v1 = v1 > 0.f ? v1 : __expf(v1) - 1.f;
  #pragma unroll
  for (int o=0;o<4;o++){
    float p = fc_w[o*128 + ch0]*v0 + fc_w[o*128 + ch1]*v1;
    #pragma unroll
    for (int d=1; d<64; d<<=1) p += __shfl_xor(p, d);
    if (lane == 0) out[(size_t)n*4 + o] = fmaxf(p + fc_b[o], 0.f);
  }
}

extern "C" void kernel_launch(void* const* d_in, const int* in_sizes, int n_in,
                              void* d_out, int out_size, void* d_ws, size_t ws_size,
                              hipStream_t stream)
{
  (void)n_in; (void)out_size; (void)ws_size;
  const float* x          = (const float*)d_in[0];
  const int*   eidx       = (const int*)d_in[1];
  const float* eattr      = (const float*)d_in[2];
  const float* w_ih0      = (const float*)d_in[3];
  const float* w_hh0      = (const float*)d_in[4];
  const float* b_ih0      = (const float*)d_in[5];
  const float* b_hh0      = (const float*)d_in[6];
  const float* w_ih1      = (const float*)d_in[7];
  const float* w_hh1      = (const float*)d_in[8];
  const float* b_ih1      = (const float*)d_in[9];
  const float* b_hh1      = (const float*)d_in[10];
  const float* lin_w      = (const float*)d_in[11];
  const float* lin_edge_w = (const float*)d_in[12];
  const float* att_src    = (const float*)d_in[13];
  const float* att_dst    = (const float*)d_in[14];
  const float* att_edge   = (const float*)d_in[15];
  const float* gat_bias   = (const float*)d_in[16];
  const float* fc_w       = (const float*)d_in[17];
  const float* fc_b       = (const float*)d_in[18];
  float* out = (float*)d_out;

  const int N = in_sizes[0] / 32;
  const int E = in_sizes[1] / 2;
  const int* esrc = eidx;
  const int* edst = eidx + E;

  float* ws = (float*)d_ws;
  size_t o = 0;
  unsigned short* Bfrag = (unsigned short*)(ws + o); o += 24576;   // 49152 fp16
  float* linwT  = ws + o; o += 72*128;
  float* cE     = ws + o; o += 4;
  float* eacc   = ws + o; o += 4;
  float* h2last = ws + o; o += (size_t)N*64;
  float* xl     = ws + o; o += (size_t)N*128;
  float* a_src  = ws + o; o += (size_t)N*4;
  float* a_dst  = ws + o; o += (size_t)N*4;
  int* deg      = (int*)(ws + o); o += (size_t)N;
  int* ptrA     = (int*)(ws + o); o += (size_t)N + 1;
  int* cursor   = (int*)(ws + o); o += (size_t)N;
  int* csr      = (int*)(ws + o); o += (size_t)E;

  hipMemsetAsync(deg, 0, (size_t)N*4, stream);
  hipMemsetAsync(eacc, 0, 4, stream);
  kPrep<<<229, 256, 0, stream>>>(w_hh0, w_ih1, w_hh1, lin_w, lin_edge_w, att_edge,
                                 Bfrag, linwT, cE);
  kEa<<<512, 256, 0, stream>>>(eattr, eacc, E);
  kDeg<<<(E+255)/256, 256, 0, stream>>>(edst, deg, E, N);
  kScan<<<1, 1024, 0, stream>>>(deg, ptrA, cursor, N);
  kFill<<<(E+255)/256, 256, 0, stream>>>(edst, cursor, csr, E, N);

  kAB<<<(N+63)/64, 512, 0, stream>>>(x, Bfrag, w_ih0, b_ih0, b_hh0,
                                     b_ih1, b_hh1, h2last, N);

  kXL<<<(N+15)/16, 256, 0, stream>>>(h2last, x, linwT, att_src, att_dst, xl, a_src, a_dst, N);
  kAgg<<<(N+3)/4, 256, 0, stream>>>(xl, a_src, a_dst, esrc, eattr, ptrA, csr, cE, eacc,
                                    gat_bias, fc_w, fc_b, out, N, E);
}